// Round 1
// baseline (1001.948 us; speedup 1.0000x reference)
//
#include <hip/hip_runtime.h>
#include <hip/hip_bf16.h>
#include <stdint.h>

#define THREADS 256

// ---------------------------------------------------------------------------
// Kernel 1: fused conv1+relu+pool -> conv2+relu+pool -> f[b][4096]
// One image per block, 256 threads.
// ---------------------------------------------------------------------------
__global__ __launch_bounds__(256, 2) void conv_fused_kernel(
    const float* __restrict__ x,
    const float* __restrict__ w1, const float* __restrict__ b1,
    const float* __restrict__ w2, const float* __restrict__ b2,
    float* __restrict__ f)
{
    __shared__ float xs[3][34][34];    // padded input image
    __shared__ float h1s[32][18][18];  // padded pooled conv1 output

    const int tid = threadIdx.x;
    const int b = blockIdx.x;

    // phase A: zero LDS (halos must be 0)
    float* xsf = &xs[0][0][0];
    for (int i = tid; i < 3 * 34 * 34; i += THREADS) xsf[i] = 0.0f;
    float* h1f = &h1s[0][0][0];
    for (int i = tid; i < 32 * 18 * 18; i += THREADS) h1f[i] = 0.0f;
    __syncthreads();

    // phase B: load image interior (3*32*32 = 768 float4 / 4)
    const float* xb = x + (size_t)b * 3072;
    #pragma unroll
    for (int q = 0; q < 3; ++q) {
        int idx = tid + q * THREADS;      // 0..767
        int ic  = idx >> 8;
        int rem = idx & 255;
        int y   = rem >> 3;
        int x4  = (rem & 7) << 2;
        float4 v = *(const float4*)(xb + ic * 1024 + y * 32 + x4);
        xs[ic][1 + y][1 + x4 + 0] = v.x;
        xs[ic][1 + y][1 + x4 + 1] = v.y;
        xs[ic][1 + y][1 + x4 + 2] = v.z;
        xs[ic][1 + y][1 + x4 + 3] = v.w;
    }
    __syncthreads();

    // phase C: conv1 (3x3, pad 1) + relu + maxpool2 -> h1s interior
    {
        const int py = tid >> 4;   // 0..15
        const int px = tid & 15;   // 0..15
        for (int ocb = 0; ocb < 4; ++ocb) {       // 8 out-channels per pass
            float s[8][4];
            #pragma unroll
            for (int o = 0; o < 8; ++o)
                #pragma unroll
                for (int m = 0; m < 4; ++m) s[o][m] = 0.0f;

            #pragma unroll
            for (int ic = 0; ic < 3; ++ic) {
                float p[4][4];
                #pragma unroll
                for (int t = 0; t < 4; ++t)
                    #pragma unroll
                    for (int u = 0; u < 4; ++u)
                        p[t][u] = xs[ic][2 * py + t][2 * px + u];
                #pragma unroll
                for (int o = 0; o < 8; ++o) {
                    // uniform address (loop vars only) -> scalar loads
                    const float* w = w1 + ((ocb * 8 + o) * 3 + ic) * 9;
                    float wv[9];
                    #pragma unroll
                    for (int m = 0; m < 9; ++m) wv[m] = w[m];
                    #pragma unroll
                    for (int dy = 0; dy < 2; ++dy)
                        #pragma unroll
                        for (int dx = 0; dx < 2; ++dx) {
                            float a = s[o][dy * 2 + dx];
                            #pragma unroll
                            for (int ky = 0; ky < 3; ++ky)
                                #pragma unroll
                                for (int kx = 0; kx < 3; ++kx)
                                    a = fmaf(p[dy + ky][dx + kx], wv[ky * 3 + kx], a);
                            s[o][dy * 2 + dx] = a;
                        }
                }
            }
            #pragma unroll
            for (int o = 0; o < 8; ++o) {
                int oc = ocb * 8 + o;
                float v = fmaxf(fmaxf(s[o][0], s[o][1]), fmaxf(s[o][2], s[o][3]));
                v = fmaxf(v + b1[oc], 0.0f);   // relu(max)+b == max(relu(conv+b)) pooled
                h1s[oc][1 + py][1 + px] = v;
            }
        }
    }
    __syncthreads();

    // phase D: conv2 (3x3, pad 1) + relu + maxpool2 -> f row
    {
        const int pos = tid & 63;          // 8x8 pooled positions
        const int py  = pos >> 3;
        const int px  = pos & 7;
        const int ocg = __builtin_amdgcn_readfirstlane(tid >> 6);  // wave-uniform 0..3

        float s[16][4];
        #pragma unroll
        for (int o = 0; o < 16; ++o)
            #pragma unroll
            for (int m = 0; m < 4; ++m) s[o][m] = 0.0f;

        for (int ic = 0; ic < 32; ++ic) {
            float p[4][4];
            #pragma unroll
            for (int t = 0; t < 4; ++t)
                #pragma unroll
                for (int u = 0; u < 4; ++u)
                    p[t][u] = h1s[ic][2 * py + t][2 * px + u];
            #pragma unroll
            for (int o = 0; o < 16; ++o) {
                const int oc = ocg * 16 + o;               // wave-uniform
                const float* w = w2 + (size_t)(oc * 32 + ic) * 9;
                float wv[9];
                #pragma unroll
                for (int m = 0; m < 9; ++m) wv[m] = w[m];
                #pragma unroll
                for (int dy = 0; dy < 2; ++dy)
                    #pragma unroll
                    for (int dx = 0; dx < 2; ++dx) {
                        float a = s[o][dy * 2 + dx];
                        #pragma unroll
                        for (int ky = 0; ky < 3; ++ky)
                            #pragma unroll
                            for (int kx = 0; kx < 3; ++kx)
                                a = fmaf(p[dy + ky][dx + kx], wv[ky * 3 + kx], a);
                        s[o][dy * 2 + dx] = a;
                    }
            }
        }

        float* fr = f + (size_t)b * 4096;
        #pragma unroll
        for (int o = 0; o < 16; ++o) {
            int oc = ocg * 16 + o;
            float v = fmaxf(fmaxf(s[o][0], s[o][1]), fmaxf(s[o][2], s[o][3]));
            v = fmaxf(v + b2[oc], 0.0f);
            fr[oc * 64 + pos] = v;     // flatten order: c*64 + h*8 + w
        }
    }
}

// ---------------------------------------------------------------------------
// Kernel 2: centroid squared norms c2[k] = sum_d centroids[k][d]^2
// ---------------------------------------------------------------------------
__global__ __launch_bounds__(256) void c2_kernel(const float* __restrict__ cent,
                                                 float* __restrict__ c2)
{
    const int k = blockIdx.x;   // 0..999
    const float4* row = (const float4*)(cent + (size_t)k * 4096);
    float s = 0.0f;
    #pragma unroll
    for (int q = 0; q < 4; ++q) {
        float4 v = row[threadIdx.x + q * 256];
        s = fmaf(v.x, v.x, s); s = fmaf(v.y, v.y, s);
        s = fmaf(v.z, v.z, s); s = fmaf(v.w, v.w, s);
    }
    #pragma unroll
    for (int off = 32; off >= 1; off >>= 1) s += __shfl_down(s, off, 64);
    __shared__ float wsum[4];
    int lane = threadIdx.x & 63, wv = threadIdx.x >> 6;
    if (lane == 0) wsum[wv] = s;
    __syncthreads();
    if (threadIdx.x == 0) c2[k] = wsum[0] + wsum[1] + wsum[2] + wsum[3];
}

// ---------------------------------------------------------------------------
// Kernel 3: dot = f @ cent^T tile GEMM; argmin of (c2[k] - 2*dot) per row via
// packed (monotone-float-key << 32 | k) atomicMin. Tie -> lowest k (= np.argmin).
// ---------------------------------------------------------------------------
#define BM 64
#define BN 128
#define BK 32

__global__ __launch_bounds__(256) void gemm_argmin_kernel(
    const float* __restrict__ f, const float* __restrict__ cent,
    const float* __restrict__ c2, unsigned long long* __restrict__ packed)
{
    __shared__ __align__(16) float fTt[BK][68];   // transposed: [d][row], pad->f4-aligned
    __shared__ __align__(16) float cTt[BK][132];  // transposed: [d][k_local]
    __shared__ unsigned long long red[BM];

    const int tid = threadIdx.x;
    const int rBase = (blockIdx.x & 63) * BM;
    const int kBase = (blockIdx.x >> 6) * BN;
    const int rg = tid >> 5;   // 0..7
    const int cg = tid & 31;   // 0..31

    if (tid < BM) red[tid] = ~0ULL;

    float acc[8][4];
    #pragma unroll
    for (int i = 0; i < 8; ++i)
        #pragma unroll
        for (int j = 0; j < 4; ++j) acc[i][j] = 0.0f;

    for (int d0 = 0; d0 < 4096; d0 += BK) {
        // issue global loads before the barrier (overlap with prev compute)
        float4 fv[2];
        #pragma unroll
        for (int q = 0; q < 2; ++q) {
            int idx = tid + q * THREADS;            // 0..511
            int r = idx >> 3, c = (idx & 7) << 2;
            fv[q] = *(const float4*)(f + (size_t)(rBase + r) * 4096 + d0 + c);
        }
        float4 cv[4];
        #pragma unroll
        for (int q = 0; q < 4; ++q) {
            int idx = tid + q * THREADS;            // 0..1023
            int r = idx >> 3, c = (idx & 7) << 2;
            int k = kBase + r;
            cv[q] = (k < 1000) ? *(const float4*)(cent + (size_t)k * 4096 + d0 + c)
                               : make_float4(0.f, 0.f, 0.f, 0.f);
        }
        __syncthreads();   // previous tile's compute done
        #pragma unroll
        for (int q = 0; q < 2; ++q) {
            int idx = tid + q * THREADS;
            int r = idx >> 3, c = (idx & 7) << 2;
            fTt[c + 0][r] = fv[q].x; fTt[c + 1][r] = fv[q].y;
            fTt[c + 2][r] = fv[q].z; fTt[c + 3][r] = fv[q].w;
        }
        #pragma unroll
        for (int q = 0; q < 4; ++q) {
            int idx = tid + q * THREADS;
            int r = idx >> 3, c = (idx & 7) << 2;
            cTt[c + 0][r] = cv[q].x; cTt[c + 1][r] = cv[q].y;
            cTt[c + 2][r] = cv[q].z; cTt[c + 3][r] = cv[q].w;
        }
        __syncthreads();   // staging visible

        #pragma unroll
        for (int d = 0; d < BK; ++d) {
            float4 a0 = *(const float4*)&fTt[d][rg * 8];
            float4 a1 = *(const float4*)&fTt[d][rg * 8 + 4];
            float a[8] = {a0.x, a0.y, a0.z, a0.w, a1.x, a1.y, a1.z, a1.w};
            float bb[4];
            #pragma unroll
            for (int j = 0; j < 4; ++j) bb[j] = cTt[d][cg + 32 * j];
            #pragma unroll
            for (int i = 0; i < 8; ++i)
                #pragma unroll
                for (int j = 0; j < 4; ++j)
                    acc[i][j] = fmaf(a[i], bb[j], acc[i][j]);
        }
    }

    // epilogue: per-row argmin of (c2[k] - 2*dot)  [f2 is row-constant, sqrt monotone]
    #pragma unroll
    for (int i = 0; i < 8; ++i) {
        int row = rg * 8 + i;
        unsigned long long best = ~0ULL;
        #pragma unroll
        for (int j = 0; j < 4; ++j) {
            int k = kBase + cg + 32 * j;
            if (k < 1000) {
                float v = c2[k] - 2.0f * acc[i][j];
                unsigned int bi = __float_as_uint(v);
                bi = (bi & 0x80000000u) ? ~bi : (bi | 0x80000000u);  // monotone key
                unsigned long long key = ((unsigned long long)bi << 32) | (unsigned int)k;
                if (key < best) best = key;
            }
        }
        atomicMin(&red[row], best);
    }
    __syncthreads();
    if (tid < BM) atomicMin(&packed[rBase + tid], red[tid]);
}

// ---------------------------------------------------------------------------
// Kernel 4: unpack argmin index
// ---------------------------------------------------------------------------
__global__ __launch_bounds__(256) void extract_kernel(
    const unsigned long long* __restrict__ packed, int* __restrict__ out)
{
    int i = blockIdx.x * 256 + threadIdx.x;
    out[i] = (int)(unsigned int)(packed[i] & 0xFFFFFFFFull);
}

// ---------------------------------------------------------------------------
extern "C" void kernel_launch(void* const* d_in, const int* in_sizes, int n_in,
                              void* d_out, int out_size, void* d_ws, size_t ws_size,
                              hipStream_t stream)
{
    const float* x    = (const float*)d_in[0];
    const float* w1   = (const float*)d_in[1];
    const float* b1   = (const float*)d_in[2];
    const float* w2   = (const float*)d_in[3];
    const float* b2   = (const float*)d_in[4];
    const float* cent = (const float*)d_in[5];
    int* out = (int*)d_out;

    char* ws = (char*)d_ws;
    float* f  = (float*)ws;                                   // 4096*4096*4 = 67108864 B
    float* c2 = (float*)(ws + 67108864);                      // 4096 B
    unsigned long long* packed =
        (unsigned long long*)(ws + 67108864 + 4096);          // 32768 B

    hipMemsetAsync(packed, 0xFF, 4096 * sizeof(unsigned long long), stream);
    conv_fused_kernel<<<4096, 256, 0, stream>>>(x, w1, b1, w2, b2, f);
    c2_kernel<<<1000, 256, 0, stream>>>(cent, c2);
    gemm_argmin_kernel<<<512, 256, 0, stream>>>(f, cent, c2, packed);
    extract_kernel<<<16, 256, 0, stream>>>(packed, out);
}

// Round 2
// 591.274 us; speedup vs baseline: 1.6946x; 1.6946x over previous
//
#include <hip/hip_runtime.h>
#include <hip/hip_bf16.h>
#include <stdint.h>

#define THREADS 256

typedef unsigned short u16;
typedef __attribute__((ext_vector_type(8))) short bf16x8;
typedef __attribute__((ext_vector_type(4))) float f32x4;

// round-to-nearest-even fp32 -> bf16 bits
__device__ inline u16 f2bf(float x) {
    unsigned u = __float_as_uint(x);
    unsigned r = (u + 0x7FFFu + ((u >> 16) & 1u)) >> 16;
    return (u16)r;
}
__device__ inline float bf2f(u16 h) { return __uint_as_float(((unsigned)h) << 16); }

__device__ inline void load_lds16(const void* g, void* l) {
    __builtin_amdgcn_global_load_lds(
        (const __attribute__((address_space(1))) unsigned int*)g,
        (__attribute__((address_space(3))) unsigned int*)l, 16, 0, 0);
}

// ---------------------------------------------------------------------------
// Kernel 1: fused conv1+relu+pool -> conv2+relu+pool -> f_hi/f_lo bf16 planes
// One image per block, 256 threads.
// ---------------------------------------------------------------------------
__global__ __launch_bounds__(256, 2) void conv_fused_kernel(
    const float* __restrict__ x,
    const float* __restrict__ w1, const float* __restrict__ b1,
    const float* __restrict__ w2, const float* __restrict__ b2,
    u16* __restrict__ f_hi, u16* __restrict__ f_lo)
{
    __shared__ float xs[3][34][34];    // padded input image
    __shared__ float h1s[32][18][18];  // padded pooled conv1 output

    const int tid = threadIdx.x;
    const int b = blockIdx.x;

    // phase A: zero LDS (halos must be 0)
    float* xsf = &xs[0][0][0];
    for (int i = tid; i < 3 * 34 * 34; i += THREADS) xsf[i] = 0.0f;
    float* h1f = &h1s[0][0][0];
    for (int i = tid; i < 32 * 18 * 18; i += THREADS) h1f[i] = 0.0f;
    __syncthreads();

    // phase B: load image interior
    const float* xb = x + (size_t)b * 3072;
    #pragma unroll
    for (int q = 0; q < 3; ++q) {
        int idx = tid + q * THREADS;      // 0..767
        int ic  = idx >> 8;
        int rem = idx & 255;
        int y   = rem >> 3;
        int x4  = (rem & 7) << 2;
        float4 v = *(const float4*)(xb + ic * 1024 + y * 32 + x4);
        xs[ic][1 + y][1 + x4 + 0] = v.x;
        xs[ic][1 + y][1 + x4 + 1] = v.y;
        xs[ic][1 + y][1 + x4 + 2] = v.z;
        xs[ic][1 + y][1 + x4 + 3] = v.w;
    }
    __syncthreads();

    // phase C: conv1 + relu + maxpool2 -> h1s interior
    {
        const int py = tid >> 4;   // 0..15
        const int px = tid & 15;   // 0..15
        for (int ocb = 0; ocb < 4; ++ocb) {
            float s[8][4];
            #pragma unroll
            for (int o = 0; o < 8; ++o)
                #pragma unroll
                for (int m = 0; m < 4; ++m) s[o][m] = 0.0f;

            #pragma unroll
            for (int ic = 0; ic < 3; ++ic) {
                float p[4][4];
                #pragma unroll
                for (int t = 0; t < 4; ++t)
                    #pragma unroll
                    for (int u = 0; u < 4; ++u)
                        p[t][u] = xs[ic][2 * py + t][2 * px + u];
                #pragma unroll
                for (int o = 0; o < 8; ++o) {
                    const float* w = w1 + ((ocb * 8 + o) * 3 + ic) * 9;
                    float wv[9];
                    #pragma unroll
                    for (int m = 0; m < 9; ++m) wv[m] = w[m];
                    #pragma unroll
                    for (int dy = 0; dy < 2; ++dy)
                        #pragma unroll
                        for (int dx = 0; dx < 2; ++dx) {
                            float a = s[o][dy * 2 + dx];
                            #pragma unroll
                            for (int ky = 0; ky < 3; ++ky)
                                #pragma unroll
                                for (int kx = 0; kx < 3; ++kx)
                                    a = fmaf(p[dy + ky][dx + kx], wv[ky * 3 + kx], a);
                            s[o][dy * 2 + dx] = a;
                        }
                }
            }
            #pragma unroll
            for (int o = 0; o < 8; ++o) {
                int oc = ocb * 8 + o;
                float v = fmaxf(fmaxf(s[o][0], s[o][1]), fmaxf(s[o][2], s[o][3]));
                v = fmaxf(v + b1[oc], 0.0f);
                h1s[oc][1 + py][1 + px] = v;
            }
        }
    }
    __syncthreads();

    // phase D: conv2 + relu + maxpool2 -> f row (split bf16 hi/lo)
    {
        const int pos = tid & 63;
        const int py  = pos >> 3;
        const int px  = pos & 7;
        const int ocg = __builtin_amdgcn_readfirstlane(tid >> 6);

        float s[16][4];
        #pragma unroll
        for (int o = 0; o < 16; ++o)
            #pragma unroll
            for (int m = 0; m < 4; ++m) s[o][m] = 0.0f;

        for (int ic = 0; ic < 32; ++ic) {
            float p[4][4];
            #pragma unroll
            for (int t = 0; t < 4; ++t)
                #pragma unroll
                for (int u = 0; u < 4; ++u)
                    p[t][u] = h1s[ic][2 * py + t][2 * px + u];
            #pragma unroll
            for (int o = 0; o < 16; ++o) {
                const int oc = ocg * 16 + o;
                const float* w = w2 + (size_t)(oc * 32 + ic) * 9;
                float wv[9];
                #pragma unroll
                for (int m = 0; m < 9; ++m) wv[m] = w[m];
                #pragma unroll
                for (int dy = 0; dy < 2; ++dy)
                    #pragma unroll
                    for (int dx = 0; dx < 2; ++dx) {
                        float a = s[o][dy * 2 + dx];
                        #pragma unroll
                        for (int ky = 0; ky < 3; ++ky)
                            #pragma unroll
                            for (int kx = 0; kx < 3; ++kx)
                                a = fmaf(p[dy + ky][dx + kx], wv[ky * 3 + kx], a);
                        s[o][dy * 2 + dx] = a;
                    }
            }
        }

        const size_t base = (size_t)b * 4096;
        #pragma unroll
        for (int o = 0; o < 16; ++o) {
            int oc = ocg * 16 + o;
            float v = fmaxf(fmaxf(s[o][0], s[o][1]), fmaxf(s[o][2], s[o][3]));
            v = fmaxf(v + b2[oc], 0.0f);
            u16 hb = f2bf(v);
            u16 lb = f2bf(v - bf2f(hb));
            f_hi[base + oc * 64 + pos] = hb;
            f_lo[base + oc * 64 + pos] = lb;
        }
    }
}

// ---------------------------------------------------------------------------
// Kernel 2: centroid squared norms (fp32)
// ---------------------------------------------------------------------------
__global__ __launch_bounds__(256) void c2_kernel(const float* __restrict__ cent,
                                                 float* __restrict__ c2)
{
    const int k = blockIdx.x;   // 0..999
    const float4* row = (const float4*)(cent + (size_t)k * 4096);
    float s = 0.0f;
    #pragma unroll
    for (int q = 0; q < 4; ++q) {
        float4 v = row[threadIdx.x + q * 256];
        s = fmaf(v.x, v.x, s); s = fmaf(v.y, v.y, s);
        s = fmaf(v.z, v.z, s); s = fmaf(v.w, v.w, s);
    }
    #pragma unroll
    for (int off = 32; off >= 1; off >>= 1) s += __shfl_down(s, off, 64);
    __shared__ float wsum[4];
    int lane = threadIdx.x & 63, wv = threadIdx.x >> 6;
    if (lane == 0) wsum[wv] = s;
    __syncthreads();
    if (threadIdx.x == 0) c2[k] = wsum[0] + wsum[1] + wsum[2] + wsum[3];
}

// ---------------------------------------------------------------------------
// Kernel 3: split centroids into bf16 hi/lo planes (padded to 1024 rows)
// ---------------------------------------------------------------------------
__global__ __launch_bounds__(256) void cent_split_kernel(
    const float* __restrict__ cent, u16* __restrict__ c_hi, u16* __restrict__ c_lo)
{
    const int n = blockIdx.x;     // 0..1023
    const int t = threadIdx.x;
    const size_t base = (size_t)n * 4096;
    if (n < 1000) {
        #pragma unroll
        for (int q = 0; q < 4; ++q) {
            int e = (t + q * 256) * 4;
            float4 v = *(const float4*)(cent + base + e);
            ushort4 h, l;
            h.x = f2bf(v.x); l.x = f2bf(v.x - bf2f(h.x));
            h.y = f2bf(v.y); l.y = f2bf(v.y - bf2f(h.y));
            h.z = f2bf(v.z); l.z = f2bf(v.z - bf2f(h.z));
            h.w = f2bf(v.w); l.w = f2bf(v.w - bf2f(h.w));
            *(ushort4*)(c_hi + base + e) = h;
            *(ushort4*)(c_lo + base + e) = l;
        }
    } else {
        ushort4 z; z.x = z.y = z.z = z.w = 0;
        #pragma unroll
        for (int q = 0; q < 4; ++q) {
            int e = (t + q * 256) * 4;
            *(ushort4*)(c_hi + base + e) = z;
            *(ushort4*)(c_lo + base + e) = z;
        }
    }
}

// ---------------------------------------------------------------------------
// Kernel 4: split-bf16 MFMA GEMM (f . cent^T) + fused argmin epilogue.
// 128x64 tile, BK=32, 4 waves (2Mx2N), 16x16x32 bf16 MFMA, 4-term split:
// hi*hi + hi*lo + lo*hi + lo*lo  ~= fp32 product (rel err ~2^-18).
// global_load_lds staging, pre-swizzled source (slot ^= (row>>1)&3) so
// ds_read_b128 is 2-way (free) instead of 8-way.
// ---------------------------------------------------------------------------
#define GBM 128
#define GBN 64
#define GBK 32

__global__ __launch_bounds__(256, 2) void gemm_argmin_mfma(
    const u16* __restrict__ f_hi, const u16* __restrict__ f_lo,
    const u16* __restrict__ c_hi, const u16* __restrict__ c_lo,
    const float* __restrict__ c2, unsigned long long* __restrict__ packed)
{
    __shared__ __align__(16) u16 Ah[GBM * GBK];
    __shared__ __align__(16) u16 Al[GBM * GBK];
    __shared__ __align__(16) u16 Bh[GBN * GBK];
    __shared__ __align__(16) u16 Bl[GBN * GBK];
    __shared__ unsigned long long red[GBM];

    const int tid = threadIdx.x;
    const int nb = blockIdx.x & 15;   // consecutive blocks share the A panel (L2)
    const int mb = blockIdx.x >> 4;
    const int m0 = mb * GBM;
    const int n0 = nb * GBN;

    const int lane = tid & 63;
    const int wid  = tid >> 6;
    const int wm = wid >> 1, wn = wid & 1;
    const int li = lane & 15;
    const int ls = lane >> 4;
    const int swz = (li >> 1) & 3;
    const int rslot = (ls ^ swz) << 4;   // byte offset of this lane's 16B slot

    if (tid < GBM) red[tid] = ~0ULL;

    f32x4 acc[4][2];
    #pragma unroll
    for (int i = 0; i < 4; ++i)
        #pragma unroll
        for (int j = 0; j < 2; ++j) acc[i][j] = (f32x4){0.f, 0.f, 0.f, 0.f};

    for (int k0 = 0; k0 < 4096; k0 += GBK) {
        // stage tile (linear LDS dest; swizzle applied on the global source)
        #pragma unroll
        for (int q = 0; q < 2; ++q) {
            int idx = tid + q * 256;          // 0..511
            int row = idx >> 2, slot = idx & 3;
            int kg = k0 + ((slot ^ ((row >> 1) & 3)) << 3);
            size_t goff = (size_t)(m0 + row) * 4096 + kg;
            load_lds16(f_hi + goff, &Ah[idx * 8]);
            load_lds16(f_lo + goff, &Al[idx * 8]);
        }
        {
            int idx = tid;                    // 0..255
            int row = idx >> 2, slot = idx & 3;
            int kg = k0 + ((slot ^ ((row >> 1) & 3)) << 3);
            size_t goff = (size_t)(n0 + row) * 4096 + kg;
            load_lds16(c_hi + goff, &Bh[idx * 8]);
            load_lds16(c_lo + goff, &Bl[idx * 8]);
        }
        __syncthreads();   // drains vmcnt -> tile resident

        bf16x8 ah[4], al[4], bh[2], bl[2];
        #pragma unroll
        for (int mt = 0; mt < 4; ++mt) {
            int r = wm * 64 + mt * 16 + li;
            int byte = r * 64 + rslot;
            ah[mt] = *(const bf16x8*)((const char*)Ah + byte);
            al[mt] = *(const bf16x8*)((const char*)Al + byte);
        }
        #pragma unroll
        for (int nt = 0; nt < 2; ++nt) {
            int r = wn * 32 + nt * 16 + li;
            int byte = r * 64 + rslot;
            bh[nt] = *(const bf16x8*)((const char*)Bh + byte);
            bl[nt] = *(const bf16x8*)((const char*)Bl + byte);
        }
        #pragma unroll
        for (int mt = 0; mt < 4; ++mt)
            #pragma unroll
            for (int nt = 0; nt < 2; ++nt) {
                acc[mt][nt] = __builtin_amdgcn_mfma_f32_16x16x32_bf16(ah[mt], bh[nt], acc[mt][nt], 0, 0, 0);
                acc[mt][nt] = __builtin_amdgcn_mfma_f32_16x16x32_bf16(ah[mt], bl[nt], acc[mt][nt], 0, 0, 0);
                acc[mt][nt] = __builtin_amdgcn_mfma_f32_16x16x32_bf16(al[mt], bh[nt], acc[mt][nt], 0, 0, 0);
                acc[mt][nt] = __builtin_amdgcn_mfma_f32_16x16x32_bf16(al[mt], bl[nt], acc[mt][nt], 0, 0, 0);
            }
        __syncthreads();   // before next-tile overwrite
    }

    // epilogue: argmin of (c2[n] - 2*dot) per row. C/D layout: col=lane&15,
    // row=(lane>>4)*4+reg (m89). Key = monotone-float<<32 | n; tie -> lowest n.
    #pragma unroll
    for (int mt = 0; mt < 4; ++mt) {
        #pragma unroll
        for (int reg = 0; reg < 4; ++reg) {
            unsigned long long best = ~0ULL;
            #pragma unroll
            for (int nt = 0; nt < 2; ++nt) {
                int n = n0 + wn * 32 + nt * 16 + li;
                if (n < 1000) {
                    float v = c2[n] - 2.0f * acc[mt][nt][reg];
                    unsigned bi = __float_as_uint(v);
                    bi = (bi & 0x80000000u) ? ~bi : (bi | 0x80000000u);
                    unsigned long long key = ((unsigned long long)bi << 32) | (unsigned)n;
                    if (key < best) best = key;
                }
            }
            #pragma unroll
            for (int d = 1; d < 16; d <<= 1) {
                unsigned long long o = __shfl_xor(best, d, 64);
                if (o < best) best = o;
            }
            if (li == 0) {
                int lr = wm * 64 + mt * 16 + ls * 4 + reg;
                atomicMin(&red[lr], best);
            }
        }
    }
    __syncthreads();
    if (tid < GBM) atomicMin(&packed[m0 + tid], red[tid]);
}

// ---------------------------------------------------------------------------
// Kernel 5: unpack argmin index
// ---------------------------------------------------------------------------
__global__ __launch_bounds__(256) void extract_kernel(
    const unsigned long long* __restrict__ packed, int* __restrict__ out)
{
    int i = blockIdx.x * 256 + threadIdx.x;
    out[i] = (int)(unsigned)(packed[i] & 0xFFFFFFFFull);
}

// ---------------------------------------------------------------------------
extern "C" void kernel_launch(void* const* d_in, const int* in_sizes, int n_in,
                              void* d_out, int out_size, void* d_ws, size_t ws_size,
                              hipStream_t stream)
{
    const float* x    = (const float*)d_in[0];
    const float* w1   = (const float*)d_in[1];
    const float* b1   = (const float*)d_in[2];
    const float* w2   = (const float*)d_in[3];
    const float* b2   = (const float*)d_in[4];
    const float* cent = (const float*)d_in[5];
    int* out = (int*)d_out;

    char* ws = (char*)d_ws;
    u16* f_hi = (u16*)(ws);                          // 4096*4096*2 = 33554432
    u16* f_lo = (u16*)(ws + 33554432);               // 33554432
    u16* c_hi = (u16*)(ws + 67108864);               // 1024*4096*2 = 8388608
    u16* c_lo = (u16*)(ws + 75497472);               // 8388608
    float* c2 = (float*)(ws + 83886080);             // 1024*4 = 4096
    unsigned long long* packed =
        (unsigned long long*)(ws + 83890176);        // 4096*8 = 32768

    hipMemsetAsync(packed, 0xFF, 4096 * sizeof(unsigned long long), stream);
    conv_fused_kernel<<<4096, 256, 0, stream>>>(x, w1, b1, w2, b2, f_hi, f_lo);
    cent_split_kernel<<<1024, 256, 0, stream>>>(cent, c_hi, c_lo);
    c2_kernel<<<1000, 256, 0, stream>>>(cent, c2);
    gemm_argmin_mfma<<<512, 256, 0, stream>>>(f_hi, f_lo, c_hi, c_lo, c2, packed);
    extract_kernel<<<16, 256, 0, stream>>>(packed, out);
}

// Round 3
// 362.940 us; speedup vs baseline: 2.7606x; 1.6291x over previous
//
#include <hip/hip_runtime.h>
#include <hip/hip_bf16.h>
#include <stdint.h>

#define THREADS 256

typedef unsigned short u16;
typedef __attribute__((ext_vector_type(8))) short bf16x8;
typedef __attribute__((ext_vector_type(4))) float f32x4;

// round-to-nearest-even fp32 -> bf16 bits
__device__ inline u16 f2bf(float x) {
    unsigned u = __float_as_uint(x);
    unsigned r = (u + 0x7FFFu + ((u >> 16) & 1u)) >> 16;
    return (u16)r;
}
__device__ inline float bf2f(u16 h) { return __uint_as_float(((unsigned)h) << 16); }

__device__ inline void load_lds16(const void* g, void* l) {
    __builtin_amdgcn_global_load_lds(
        (const __attribute__((address_space(1))) unsigned int*)g,
        (__attribute__((address_space(3))) unsigned int*)l, 16, 0, 0);
}

// ---------------------------------------------------------------------------
// Kernel 0: pre-permute w2 into per-lane MFMA A-fragments (split bf16).
// Layout: w2t[tap][plane][mt][lane][j8] flat; lane's 16B = one bf16x8 frag.
// oc = mt*16 + (lane&15), ic = (lane>>4)*8 + j.
// ---------------------------------------------------------------------------
__global__ __launch_bounds__(256) void w2t_prep_kernel(
    const float* __restrict__ w2, u16* __restrict__ w2t)
{
    int idx = blockIdx.x * 256 + threadIdx.x;   // 0..36863
    int j     = idx & 7;
    int lane  = (idx >> 3) & 63;
    int mt    = (idx >> 9) & 3;
    int plane = (idx >> 11) & 1;
    int tap   = idx >> 12;                      // 0..8
    int oc = mt * 16 + (lane & 15);
    int ic = (lane >> 4) * 8 + j;
    float v = w2[(size_t)oc * 288 + ic * 9 + tap];
    u16 hb = f2bf(v);
    w2t[idx] = plane ? f2bf(v - bf2f(hb)) : hb;
}

// ---------------------------------------------------------------------------
// Kernel 1: fused conv1(fp32 VALU) + conv2(split-bf16 MFMA) + pools -> f
// One image per block, 256 threads (4 waves).
// ---------------------------------------------------------------------------
__global__ __launch_bounds__(256, 2) void conv_fused_kernel(
    const float* __restrict__ x,
    const float* __restrict__ w1, const float* __restrict__ b1,
    const u16* __restrict__ w2t, const float* __restrict__ b2,
    u16* __restrict__ f_hi, u16* __restrict__ f_lo)
{
    __shared__ float xs[3][34][34];                     // padded input image
    __shared__ __align__(16) u16 h1hi[18 * 18 * 32];    // [y][x][ic] bf16 hi
    __shared__ __align__(16) u16 h1lo[18 * 18 * 32];    // [y][x][ic] bf16 lo

    const int tid = threadIdx.x;
    const int b = blockIdx.x;

    // phase A: zero LDS (halos must be 0)
    float* xsf = &xs[0][0][0];
    for (int i = tid; i < 3 * 34 * 34; i += THREADS) xsf[i] = 0.0f;
    {
        int4* z0 = (int4*)h1hi;  // 20736 B = 1296 int4
        int4* z1 = (int4*)h1lo;
        int4 zz = make_int4(0, 0, 0, 0);
        for (int i = tid; i < 1296; i += THREADS) { z0[i] = zz; z1[i] = zz; }
    }
    __syncthreads();

    // phase B: load image interior
    const float* xb = x + (size_t)b * 3072;
    #pragma unroll
    for (int q = 0; q < 3; ++q) {
        int idx = tid + q * THREADS;      // 0..767
        int ic  = idx >> 8;
        int rem = idx & 255;
        int y   = rem >> 3;
        int x4  = (rem & 7) << 2;
        float4 v = *(const float4*)(xb + ic * 1024 + y * 32 + x4);
        xs[ic][1 + y][1 + x4 + 0] = v.x;
        xs[ic][1 + y][1 + x4 + 1] = v.y;
        xs[ic][1 + y][1 + x4 + 2] = v.z;
        xs[ic][1 + y][1 + x4 + 3] = v.w;
    }
    __syncthreads();

    // phase C: conv1 + relu + maxpool2 -> h1 (split bf16, swizzled b128 writes)
    {
        const int py = tid >> 4;   // 0..15
        const int px = tid & 15;   // 0..15
        const int xx = 1 + px, yy = 1 + py;
        const int sbase = (yy * 18 + xx) * 64;   // byte base of this (y,x) cell
        for (int ib = 0; ib < 4; ++ib) {         // 8 out-channels per pass
            float s[8][4];
            #pragma unroll
            for (int o = 0; o < 8; ++o)
                #pragma unroll
                for (int m = 0; m < 4; ++m) s[o][m] = 0.0f;

            #pragma unroll
            for (int ic = 0; ic < 3; ++ic) {
                float p[4][4];
                #pragma unroll
                for (int t = 0; t < 4; ++t)
                    #pragma unroll
                    for (int u = 0; u < 4; ++u)
                        p[t][u] = xs[ic][2 * py + t][2 * px + u];
                #pragma unroll
                for (int o = 0; o < 8; ++o) {
                    const float* w = w1 + ((ib * 8 + o) * 3 + ic) * 9;
                    float wv[9];
                    #pragma unroll
                    for (int m = 0; m < 9; ++m) wv[m] = w[m];
                    #pragma unroll
                    for (int dy = 0; dy < 2; ++dy)
                        #pragma unroll
                        for (int dx = 0; dx < 2; ++dx) {
                            float a = s[o][dy * 2 + dx];
                            #pragma unroll
                            for (int ky = 0; ky < 3; ++ky)
                                #pragma unroll
                                for (int kx = 0; kx < 3; ++kx)
                                    a = fmaf(p[dy + ky][dx + kx], wv[ky * 3 + kx], a);
                            s[o][dy * 2 + dx] = a;
                        }
                }
            }
            bf16x8 ph, pl;
            #pragma unroll
            for (int o = 0; o < 8; ++o) {
                int oc = ib * 8 + o;
                float v = fmaxf(fmaxf(s[o][0], s[o][1]), fmaxf(s[o][2], s[o][3]));
                v = fmaxf(v + b1[oc], 0.0f);
                u16 hb = f2bf(v);
                ph[o] = (short)hb;
                pl[o] = (short)f2bf(v - bf2f(hb));
            }
            int byte = sbase + ((ib ^ ((xx >> 1) & 3)) << 4);
            *(bf16x8*)((char*)h1hi + byte) = ph;
            *(bf16x8*)((char*)h1lo + byte) = pl;
        }
    }
    __syncthreads();

    // phase D: conv2 via split-bf16 MFMA (9 taps x K=32), pool, bias, relu, store
    {
        const int lane = tid & 63;
        const int li = lane & 15, ls = lane >> 4;
        const int wv = tid >> 6;            // wave: owns output rows 4w..4w+3

        f32x4 acc[4][4];                    // [mt][ntl]
        #pragma unroll
        for (int i = 0; i < 4; ++i)
            #pragma unroll
            for (int j = 0; j < 4; ++j) acc[i][j] = (f32x4){0.f, 0.f, 0.f, 0.f};

        #pragma unroll
        for (int ky = 0; ky < 3; ++ky) {
            #pragma unroll
            for (int kx = 0; kx < 3; ++kx) {
                const int tap = ky * 3 + kx;
                // A fragments (global, L2-hot, lane-contiguous)
                bf16x8 aH[4], aL[4];
                #pragma unroll
                for (int mt = 0; mt < 4; ++mt) {
                    aH[mt] = *(const bf16x8*)(w2t + (size_t)(tap * 4096 + 0 * 2048 + mt * 512 + lane * 8));
                    aL[mt] = *(const bf16x8*)(w2t + (size_t)(tap * 4096 + 1 * 2048 + mt * 512 + lane * 8));
                }
                // B fragments from h1 LDS (one b128 per plane per ntl)
                bf16x8 bH[4], bL[4];
                #pragma unroll
                for (int ntl = 0; ntl < 4; ++ntl) {
                    int y = 4 * wv + ntl + ky;     // 0..17
                    int xcol = li + kx;            // 0..17
                    int byte = (y * 18 + xcol) * 64 + ((ls ^ ((xcol >> 1) & 3)) << 4);
                    bH[ntl] = *(const bf16x8*)((const char*)h1hi + byte);
                    bL[ntl] = *(const bf16x8*)((const char*)h1lo + byte);
                }
                #pragma unroll
                for (int mt = 0; mt < 4; ++mt)
                    #pragma unroll
                    for (int ntl = 0; ntl < 4; ++ntl) {
                        acc[mt][ntl] = __builtin_amdgcn_mfma_f32_16x16x32_bf16(aH[mt], bH[ntl], acc[mt][ntl], 0, 0, 0);
                        acc[mt][ntl] = __builtin_amdgcn_mfma_f32_16x16x32_bf16(aH[mt], bL[ntl], acc[mt][ntl], 0, 0, 0);
                        acc[mt][ntl] = __builtin_amdgcn_mfma_f32_16x16x32_bf16(aL[mt], bH[ntl], acc[mt][ntl], 0, 0, 0);
                        acc[mt][ntl] = __builtin_amdgcn_mfma_f32_16x16x32_bf16(aL[mt], bL[ntl], acc[mt][ntl], 0, 0, 0);
                    }
            }
        }

        // epilogue: 2x2 maxpool (shfl_xor x-pairs, in-thread y-pairs), bias, relu
        const size_t fbase = (size_t)b * 4096;
        #pragma unroll
        for (int mt = 0; mt < 4; ++mt) {
            #pragma unroll
            for (int reg = 0; reg < 4; ++reg) {
                int oc = mt * 16 + ls * 4 + reg;
                float bias = b2[oc];
                #pragma unroll
                for (int p = 0; p < 2; ++p) {
                    float v0 = acc[mt][2 * p + 0][reg];
                    float v1 = acc[mt][2 * p + 1][reg];
                    float x0 = fmaxf(v0, __shfl_xor(v0, 1, 64));
                    float x1 = fmaxf(v1, __shfl_xor(v1, 1, 64));
                    float v = fmaxf(fmaxf(x0, x1) + bias, 0.0f);
                    if ((li & 1) == 0) {
                        int py = 2 * wv + p, px = li >> 1;
                        u16 hb = f2bf(v);
                        u16 lb = f2bf(v - bf2f(hb));
                        size_t o = fbase + (size_t)oc * 64 + py * 8 + px;
                        f_hi[o] = hb;
                        f_lo[o] = lb;
                    }
                }
            }
        }
    }
}

// ---------------------------------------------------------------------------
// Kernel 2: centroid squared norms (fp32)
// ---------------------------------------------------------------------------
__global__ __launch_bounds__(256) void c2_kernel(const float* __restrict__ cent,
                                                 float* __restrict__ c2)
{
    const int k = blockIdx.x;   // 0..999
    const float4* row = (const float4*)(cent + (size_t)k * 4096);
    float s = 0.0f;
    #pragma unroll
    for (int q = 0; q < 4; ++q) {
        float4 v = row[threadIdx.x + q * 256];
        s = fmaf(v.x, v.x, s); s = fmaf(v.y, v.y, s);
        s = fmaf(v.z, v.z, s); s = fmaf(v.w, v.w, s);
    }
    #pragma unroll
    for (int off = 32; off >= 1; off >>= 1) s += __shfl_down(s, off, 64);
    __shared__ float wsum[4];
    int lane = threadIdx.x & 63, wv = threadIdx.x >> 6;
    if (lane == 0) wsum[wv] = s;
    __syncthreads();
    if (threadIdx.x == 0) c2[k] = wsum[0] + wsum[1] + wsum[2] + wsum[3];
}

// ---------------------------------------------------------------------------
// Kernel 3: split centroids into bf16 hi/lo planes (rows 0..999 only; pad rows
// 1000..1023 are read by the GEMM but their columns are guarded n<1000)
// ---------------------------------------------------------------------------
__global__ __launch_bounds__(256) void cent_split_kernel(
    const float* __restrict__ cent, u16* __restrict__ c_hi, u16* __restrict__ c_lo)
{
    const int n = blockIdx.x;     // 0..999
    const int t = threadIdx.x;
    const size_t base = (size_t)n * 4096;
    #pragma unroll
    for (int q = 0; q < 4; ++q) {
        int e = (t + q * 256) * 4;
        float4 v = *(const float4*)(cent + base + e);
        ushort4 h, l;
        h.x = f2bf(v.x); l.x = f2bf(v.x - bf2f(h.x));
        h.y = f2bf(v.y); l.y = f2bf(v.y - bf2f(h.y));
        h.z = f2bf(v.z); l.z = f2bf(v.z - bf2f(h.z));
        h.w = f2bf(v.w); l.w = f2bf(v.w - bf2f(h.w));
        *(ushort4*)(c_hi + base + e) = h;
        *(ushort4*)(c_lo + base + e) = l;
    }
}

// ---------------------------------------------------------------------------
// Kernel 4: split-bf16 MFMA GEMM (f . cent^T) + fused argmin epilogue.
// ---------------------------------------------------------------------------
#define GBM 128
#define GBN 64
#define GBK 32

__global__ __launch_bounds__(256, 2) void gemm_argmin_mfma(
    const u16* __restrict__ f_hi, const u16* __restrict__ f_lo,
    const u16* __restrict__ c_hi, const u16* __restrict__ c_lo,
    const float* __restrict__ c2, unsigned long long* __restrict__ packed)
{
    __shared__ __align__(16) u16 Ah[GBM * GBK];
    __shared__ __align__(16) u16 Al[GBM * GBK];
    __shared__ __align__(16) u16 Bh[GBN * GBK];
    __shared__ __align__(16) u16 Bl[GBN * GBK];
    __shared__ unsigned long long red[GBM];

    const int tid = threadIdx.x;
    const int nb = blockIdx.x & 15;   // consecutive blocks share the A panel (L2)
    const int mb = blockIdx.x >> 4;
    const int m0 = mb * GBM;
    const int n0 = nb * GBN;

    const int lane = tid & 63;
    const int wid  = tid >> 6;
    const int wm = wid >> 1, wn = wid & 1;
    const int li = lane & 15;
    const int ls = lane >> 4;
    const int swz = (li >> 1) & 3;
    const int rslot = (ls ^ swz) << 4;   // byte offset of this lane's 16B slot

    if (tid < GBM) red[tid] = ~0ULL;

    f32x4 acc[4][2];
    #pragma unroll
    for (int i = 0; i < 4; ++i)
        #pragma unroll
        for (int j = 0; j < 2; ++j) acc[i][j] = (f32x4){0.f, 0.f, 0.f, 0.f};

    for (int k0 = 0; k0 < 4096; k0 += GBK) {
        #pragma unroll
        for (int q = 0; q < 2; ++q) {
            int idx = tid + q * 256;          // 0..511
            int row = idx >> 2, slot = idx & 3;
            int kg = k0 + ((slot ^ ((row >> 1) & 3)) << 3);
            size_t goff = (size_t)(m0 + row) * 4096 + kg;
            load_lds16(f_hi + goff, &Ah[idx * 8]);
            load_lds16(f_lo + goff, &Al[idx * 8]);
        }
        {
            int idx = tid;                    // 0..255
            int row = idx >> 2, slot = idx & 3;
            int kg = k0 + ((slot ^ ((row >> 1) & 3)) << 3);
            size_t goff = (size_t)(n0 + row) * 4096 + kg;
            load_lds16(c_hi + goff, &Bh[idx * 8]);
            load_lds16(c_lo + goff, &Bl[idx * 8]);
        }
        __syncthreads();   // drains vmcnt -> tile resident

        bf16x8 ah[4], al[4], bh[2], bl[2];
        #pragma unroll
        for (int mt = 0; mt < 4; ++mt) {
            int r = wm * 64 + mt * 16 + li;
            int byte = r * 64 + rslot;
            ah[mt] = *(const bf16x8*)((const char*)Ah + byte);
            al[mt] = *(const bf16x8*)((const char*)Al + byte);
        }
        #pragma unroll
        for (int nt = 0; nt < 2; ++nt) {
            int r = wn * 32 + nt * 16 + li;
            int byte = r * 64 + rslot;
            bh[nt] = *(const bf16x8*)((const char*)Bh + byte);
            bl[nt] = *(const bf16x8*)((const char*)Bl + byte);
        }
        #pragma unroll
        for (int mt = 0; mt < 4; ++mt)
            #pragma unroll
            for (int nt = 0; nt < 2; ++nt) {
                acc[mt][nt] = __builtin_amdgcn_mfma_f32_16x16x32_bf16(ah[mt], bh[nt], acc[mt][nt], 0, 0, 0);
                acc[mt][nt] = __builtin_amdgcn_mfma_f32_16x16x32_bf16(ah[mt], bl[nt], acc[mt][nt], 0, 0, 0);
                acc[mt][nt] = __builtin_amdgcn_mfma_f32_16x16x32_bf16(al[mt], bh[nt], acc[mt][nt], 0, 0, 0);
                acc[mt][nt] = __builtin_amdgcn_mfma_f32_16x16x32_bf16(al[mt], bl[nt], acc[mt][nt], 0, 0, 0);
            }
        __syncthreads();   // before next-tile overwrite
    }

    // epilogue: argmin of (c2[n] - 2*dot) per row. C/D: col=lane&15, row=(lane>>4)*4+reg.
    #pragma unroll
    for (int mt = 0; mt < 4; ++mt) {
        #pragma unroll
        for (int reg = 0; reg < 4; ++reg) {
            unsigned long long best = ~0ULL;
            #pragma unroll
            for (int nt = 0; nt < 2; ++nt) {
                int n = n0 + wn * 32 + nt * 16 + li;
                if (n < 1000) {
                    float v = c2[n] - 2.0f * acc[mt][nt][reg];
                    unsigned bi = __float_as_uint(v);
                    bi = (bi & 0x80000000u) ? ~bi : (bi | 0x80000000u);
                    unsigned long long key = ((unsigned long long)bi << 32) | (unsigned)n;
                    if (key < best) best = key;
                }
            }
            #pragma unroll
            for (int d = 1; d < 16; d <<= 1) {
                unsigned long long o = __shfl_xor(best, d, 64);
                if (o < best) best = o;
            }
            if (li == 0) {
                int lr = wm * 64 + mt * 16 + ls * 4 + reg;
                atomicMin(&red[lr], best);
            }
        }
    }
    __syncthreads();
    if (tid < GBM) atomicMin(&packed[m0 + tid], red[tid]);
}

// ---------------------------------------------------------------------------
// Kernel 5: unpack argmin index
// ---------------------------------------------------------------------------
__global__ __launch_bounds__(256) void extract_kernel(
    const unsigned long long* __restrict__ packed, int* __restrict__ out)
{
    int i = blockIdx.x * 256 + threadIdx.x;
    out[i] = (int)(unsigned)(packed[i] & 0xFFFFFFFFull);
}

// ---------------------------------------------------------------------------
extern "C" void kernel_launch(void* const* d_in, const int* in_sizes, int n_in,
                              void* d_out, int out_size, void* d_ws, size_t ws_size,
                              hipStream_t stream)
{
    const float* x    = (const float*)d_in[0];
    const float* w1   = (const float*)d_in[1];
    const float* b1   = (const float*)d_in[2];
    const float* w2   = (const float*)d_in[3];
    const float* b2   = (const float*)d_in[4];
    const float* cent = (const float*)d_in[5];
    int* out = (int*)d_out;

    char* ws = (char*)d_ws;
    u16* f_hi = (u16*)(ws);                          // 4096*4096*2 = 33554432
    u16* f_lo = (u16*)(ws + 33554432);               // 33554432
    u16* c_hi = (u16*)(ws + 67108864);               // 1024*4096*2 = 8388608
    u16* c_lo = (u16*)(ws + 75497472);               // 8388608
    float* c2 = (float*)(ws + 83886080);             // 4096
    unsigned long long* packed =
        (unsigned long long*)(ws + 83890176);        // 32768
    // w2t aliased into c_hi's unused pad rows (1000..1023): 73728 B needed,
    // fits in 24*8192 = 196608 B. GEMM may read these bytes as bf16 garbage,
    // but those columns (n>=1000) are guarded out in the argmin epilogue.
    u16* w2t = c_hi + (size_t)1000 * 4096;

    hipMemsetAsync(packed, 0xFF, 4096 * sizeof(unsigned long long), stream);
    w2t_prep_kernel<<<144, 256, 0, stream>>>(w2, w2t);
    cent_split_kernel<<<1000, 256, 0, stream>>>(cent, c_hi, c_lo);
    c2_kernel<<<1000, 256, 0, stream>>>(cent, c2);
    conv_fused_kernel<<<4096, 256, 0, stream>>>(x, w1, b1, w2t, b2, f_hi, f_lo);
    gemm_argmin_mfma<<<512, 256, 0, stream>>>(f_hi, f_lo, c_hi, c_lo, c2, packed);
    extract_kernel<<<16, 256, 0, stream>>>(packed, out);
}

// Round 4
// 318.483 us; speedup vs baseline: 3.1460x; 1.1396x over previous
//
#include <hip/hip_runtime.h>
#include <hip/hip_bf16.h>
#include <stdint.h>

#define THREADS 256

typedef unsigned short u16;
typedef __attribute__((ext_vector_type(8))) short bf16x8;
typedef __attribute__((ext_vector_type(4))) float f32x4;

// round-to-nearest-even fp32 -> bf16 bits
__device__ inline u16 f2bf(float x) {
    unsigned u = __float_as_uint(x);
    unsigned r = (u + 0x7FFFu + ((u >> 16) & 1u)) >> 16;
    return (u16)r;
}
__device__ inline float bf2f(u16 h) { return __uint_as_float(((unsigned)h) << 16); }

__device__ inline void load_lds16(const void* g, void* l) {
    __builtin_amdgcn_global_load_lds(
        (const __attribute__((address_space(1))) unsigned int*)g,
        (__attribute__((address_space(3))) unsigned int*)l, 16, 0, 0);
}

// ---------------------------------------------------------------------------
// Kernel 0: pre-permute w2 into per-lane MFMA A-fragments (split bf16).
// Layout: w2t[tap][plane][mt][lane][j8]; oc = mt*16+(lane&15), ic=(lane>>4)*8+j.
// ---------------------------------------------------------------------------
__global__ __launch_bounds__(256) void w2t_prep_kernel(
    const float* __restrict__ w2, u16* __restrict__ w2t)
{
    int idx = blockIdx.x * 256 + threadIdx.x;   // 0..36863
    int j     = idx & 7;
    int lane  = (idx >> 3) & 63;
    int mt    = (idx >> 9) & 3;
    int plane = (idx >> 11) & 1;
    int tap   = idx >> 12;                      // 0..8
    int oc = mt * 16 + (lane & 15);
    int ic = (lane >> 4) * 8 + j;
    float v = w2[(size_t)oc * 288 + ic * 9 + tap];
    u16 hb = f2bf(v);
    w2t[idx] = plane ? f2bf(v - bf2f(hb)) : hb;
}

// ---------------------------------------------------------------------------
// Kernel 1: fused conv1(fp32 VALU) + conv2(split-bf16 MFMA, 3-term) -> f
// One image per block, 256 threads (4 waves), 3 blocks/CU (46.7 KB LDS).
// h1 stored WITHOUT halo [16][16][32]; conv2 boundary taps: uniform ky-skip +
// per-lane x clamp-and-zero on the B fragment.
// ---------------------------------------------------------------------------
__global__ __launch_bounds__(256, 3) void conv_fused_kernel(
    const float* __restrict__ x,
    const float* __restrict__ w1, const float* __restrict__ b1,
    const u16* __restrict__ w2t, const float* __restrict__ b2,
    u16* __restrict__ f_hi, u16* __restrict__ f_lo)
{
    __shared__ float xs[3][34][34];                     // padded input image (13.9 KB)
    __shared__ __align__(16) u16 h1hi[16 * 16 * 32];    // [y][x][ic] bf16 hi (16.4 KB)
    __shared__ __align__(16) u16 h1lo[16 * 16 * 32];    // [y][x][ic] bf16 lo (16.4 KB)

    const int tid = threadIdx.x;
    const int b = blockIdx.x;

    // phase A: zero xs (halo must be 0)
    float* xsf = &xs[0][0][0];
    for (int i = tid; i < 3 * 34 * 34; i += THREADS) xsf[i] = 0.0f;
    __syncthreads();

    // phase B: load image interior
    const float* xb = x + (size_t)b * 3072;
    #pragma unroll
    for (int q = 0; q < 3; ++q) {
        int idx = tid + q * THREADS;      // 0..767
        int ic  = idx >> 8;
        int rem = idx & 255;
        int y   = rem >> 3;
        int x4  = (rem & 7) << 2;
        float4 v = *(const float4*)(xb + ic * 1024 + y * 32 + x4);
        xs[ic][1 + y][1 + x4 + 0] = v.x;
        xs[ic][1 + y][1 + x4 + 1] = v.y;
        xs[ic][1 + y][1 + x4 + 2] = v.z;
        xs[ic][1 + y][1 + x4 + 3] = v.w;
    }
    __syncthreads();

    // phase C: conv1 + relu + maxpool2 -> h1 (2 passes x 16 oc)
    {
        const int py = tid >> 4;   // 0..15
        const int px = tid & 15;   // 0..15
        const int sbase = (py * 16 + px) * 64;   // byte base of this (y,x) cell
        #pragma unroll
        for (int ib2 = 0; ib2 < 2; ++ib2) {      // 16 out-channels per pass
            float s[16][4];
            #pragma unroll
            for (int o = 0; o < 16; ++o)
                #pragma unroll
                for (int m = 0; m < 4; ++m) s[o][m] = 0.0f;

            #pragma unroll
            for (int ic = 0; ic < 3; ++ic) {
                float p[4][4];
                #pragma unroll
                for (int t = 0; t < 4; ++t)
                    #pragma unroll
                    for (int u = 0; u < 4; ++u)
                        p[t][u] = xs[ic][2 * py + t][2 * px + u];
                #pragma unroll
                for (int o = 0; o < 16; ++o) {
                    const float* w = w1 + ((ib2 * 16 + o) * 3 + ic) * 9;
                    float wv[9];
                    #pragma unroll
                    for (int m = 0; m < 9; ++m) wv[m] = w[m];
                    #pragma unroll
                    for (int dy = 0; dy < 2; ++dy)
                        #pragma unroll
                        for (int dx = 0; dx < 2; ++dx) {
                            float a = s[o][dy * 2 + dx];
                            #pragma unroll
                            for (int ky = 0; ky < 3; ++ky)
                                #pragma unroll
                                for (int kx = 0; kx < 3; ++kx)
                                    a = fmaf(p[dy + ky][dx + kx], wv[ky * 3 + kx], a);
                            s[o][dy * 2 + dx] = a;
                        }
                }
            }
            #pragma unroll
            for (int h = 0; h < 2; ++h) {        // two 8-channel blocks
                bf16x8 ph, pl;
                #pragma unroll
                for (int o = 0; o < 8; ++o) {
                    int oo = h * 8 + o;
                    int oc = ib2 * 16 + oo;
                    float v = fmaxf(fmaxf(s[oo][0], s[oo][1]), fmaxf(s[oo][2], s[oo][3]));
                    v = fmaxf(v + b1[oc], 0.0f);
                    u16 hb = f2bf(v);
                    ph[o] = (short)hb;
                    pl[o] = (short)f2bf(v - bf2f(hb));
                }
                int ib = ib2 * 2 + h;
                int byte = sbase + ((ib ^ ((px >> 1) & 3)) << 4);
                *(bf16x8*)((char*)h1hi + byte) = ph;
                *(bf16x8*)((char*)h1lo + byte) = pl;
            }
        }
    }
    __syncthreads();

    // phase D: conv2 via split-bf16 MFMA (3-term), pool, bias, relu, store
    {
        const int lane = tid & 63;
        const int li = lane & 15, ls = lane >> 4;
        const int wv = tid >> 6;            // wave: owns output rows 4wv..4wv+3
        const bf16x8 zf = {0, 0, 0, 0, 0, 0, 0, 0};

        f32x4 acc[4][4];                    // [mt][ntl]
        #pragma unroll
        for (int i = 0; i < 4; ++i)
            #pragma unroll
            for (int j = 0; j < 4; ++j) acc[i][j] = (f32x4){0.f, 0.f, 0.f, 0.f};

        #pragma unroll
        for (int ky = 0; ky < 3; ++ky) {
            #pragma unroll
            for (int kx = 0; kx < 3; ++kx) {
                const int tap = ky * 3 + kx;
                // A fragments (global, L2-hot, lane-contiguous)
                bf16x8 aH[4], aL[4];
                #pragma unroll
                for (int mt = 0; mt < 4; ++mt) {
                    aH[mt] = *(const bf16x8*)(w2t + (size_t)(tap * 4096 + mt * 512 + lane * 8));
                    aL[mt] = *(const bf16x8*)(w2t + (size_t)(tap * 4096 + 2048 + mt * 512 + lane * 8));
                }
                // x coordinate for this lane at this kx (clamp + zero if OOB)
                int xg = li + kx - 1;                 // -1..16
                bool xo = (unsigned)xg > 15u;
                int xc = min(max(xg, 0), 15);
                int slotb = (ls ^ ((xc >> 1) & 3)) << 4;
                #pragma unroll
                for (int ntl = 0; ntl < 4; ++ntl) {
                    int yg = 4 * wv + ntl + ky - 1;   // -1..16, uniform per wave
                    if ((unsigned)yg > 15u) continue; // zero-row tap: skip (uniform)
                    int byte = (yg * 16 + xc) * 64 + slotb;
                    bf16x8 bH = *(const bf16x8*)((const char*)h1hi + byte);
                    bf16x8 bL = *(const bf16x8*)((const char*)h1lo + byte);
                    if (xo) { bH = zf; bL = zf; }
                    #pragma unroll
                    for (int mt = 0; mt < 4; ++mt) {
                        acc[mt][ntl] = __builtin_amdgcn_mfma_f32_16x16x32_bf16(aH[mt], bH, acc[mt][ntl], 0, 0, 0);
                        acc[mt][ntl] = __builtin_amdgcn_mfma_f32_16x16x32_bf16(aH[mt], bL, acc[mt][ntl], 0, 0, 0);
                        acc[mt][ntl] = __builtin_amdgcn_mfma_f32_16x16x32_bf16(aL[mt], bH, acc[mt][ntl], 0, 0, 0);
                    }
                }
            }
        }

        // epilogue: 2x2 maxpool (shfl_xor x-pairs, in-thread y-pairs), bias, relu
        const size_t fbase = (size_t)b * 4096;
        #pragma unroll
        for (int mt = 0; mt < 4; ++mt) {
            #pragma unroll
            for (int reg = 0; reg < 4; ++reg) {
                int oc = mt * 16 + ls * 4 + reg;
                float bias = b2[oc];
                #pragma unroll
                for (int p = 0; p < 2; ++p) {
                    float v0 = acc[mt][2 * p + 0][reg];
                    float v1 = acc[mt][2 * p + 1][reg];
                    float x0 = fmaxf(v0, __shfl_xor(v0, 1, 64));
                    float x1 = fmaxf(v1, __shfl_xor(v1, 1, 64));
                    float v = fmaxf(fmaxf(x0, x1) + bias, 0.0f);
                    if ((li & 1) == 0) {
                        int py = 2 * wv + p, px = li >> 1;
                        u16 hb = f2bf(v);
                        u16 lb = f2bf(v - bf2f(hb));
                        size_t o = fbase + (size_t)oc * 64 + py * 8 + px;
                        f_hi[o] = hb;
                        f_lo[o] = lb;
                    }
                }
            }
        }
    }
}

// ---------------------------------------------------------------------------
// Kernel 2: split centroids into bf16 hi/lo planes AND compute squared norms
// (fused: one pass over the 16 MB centroid array)
// ---------------------------------------------------------------------------
__global__ __launch_bounds__(256) void cent_prep_kernel(
    const float* __restrict__ cent, u16* __restrict__ c_hi, u16* __restrict__ c_lo,
    float* __restrict__ c2)
{
    const int n = blockIdx.x;     // 0..999
    const int t = threadIdx.x;
    const size_t base = (size_t)n * 4096;
    float s = 0.0f;
    #pragma unroll
    for (int q = 0; q < 4; ++q) {
        int e = (t + q * 256) * 4;
        float4 v = *(const float4*)(cent + base + e);
        s = fmaf(v.x, v.x, s); s = fmaf(v.y, v.y, s);
        s = fmaf(v.z, v.z, s); s = fmaf(v.w, v.w, s);
        ushort4 h, l;
        h.x = f2bf(v.x); l.x = f2bf(v.x - bf2f(h.x));
        h.y = f2bf(v.y); l.y = f2bf(v.y - bf2f(h.y));
        h.z = f2bf(v.z); l.z = f2bf(v.z - bf2f(h.z));
        h.w = f2bf(v.w); l.w = f2bf(v.w - bf2f(h.w));
        *(ushort4*)(c_hi + base + e) = h;
        *(ushort4*)(c_lo + base + e) = l;
    }
    #pragma unroll
    for (int off = 32; off >= 1; off >>= 1) s += __shfl_down(s, off, 64);
    __shared__ float wsum[4];
    int lane = t & 63, wv = t >> 6;
    if (lane == 0) wsum[wv] = s;
    __syncthreads();
    if (t == 0) c2[n] = wsum[0] + wsum[1] + wsum[2] + wsum[3];
}

// ---------------------------------------------------------------------------
// Kernel 3: split-bf16 MFMA GEMM (f . cent^T, 3-term) + fused argmin epilogue.
// ---------------------------------------------------------------------------
#define GBM 128
#define GBN 64
#define GBK 32

__global__ __launch_bounds__(256, 2) void gemm_argmin_mfma(
    const u16* __restrict__ f_hi, const u16* __restrict__ f_lo,
    const u16* __restrict__ c_hi, const u16* __restrict__ c_lo,
    const float* __restrict__ c2, unsigned long long* __restrict__ packed)
{
    __shared__ __align__(16) u16 Ah[GBM * GBK];
    __shared__ __align__(16) u16 Al[GBM * GBK];
    __shared__ __align__(16) u16 Bh[GBN * GBK];
    __shared__ __align__(16) u16 Bl[GBN * GBK];
    __shared__ unsigned long long red[GBM];

    const int tid = threadIdx.x;
    const int nb = blockIdx.x & 15;   // consecutive blocks share the A panel (L2)
    const int mb = blockIdx.x >> 4;
    const int m0 = mb * GBM;
    const int n0 = nb * GBN;

    const int lane = tid & 63;
    const int wid  = tid >> 6;
    const int wm = wid >> 1, wn = wid & 1;
    const int li = lane & 15;
    const int ls = lane >> 4;
    const int swz = (li >> 1) & 3;
    const int rslot = (ls ^ swz) << 4;   // byte offset of this lane's 16B slot

    if (tid < GBM) red[tid] = ~0ULL;

    f32x4 acc[4][2];
    #pragma unroll
    for (int i = 0; i < 4; ++i)
        #pragma unroll
        for (int j = 0; j < 2; ++j) acc[i][j] = (f32x4){0.f, 0.f, 0.f, 0.f};

    for (int k0 = 0; k0 < 4096; k0 += GBK) {
        #pragma unroll
        for (int q = 0; q < 2; ++q) {
            int idx = tid + q * 256;          // 0..511
            int row = idx >> 2, slot = idx & 3;
            int kg = k0 + ((slot ^ ((row >> 1) & 3)) << 3);
            size_t goff = (size_t)(m0 + row) * 4096 + kg;
            load_lds16(f_hi + goff, &Ah[idx * 8]);
            load_lds16(f_lo + goff, &Al[idx * 8]);
        }
        {
            int idx = tid;                    // 0..255
            int row = idx >> 2, slot = idx & 3;
            int kg = k0 + ((slot ^ ((row >> 1) & 3)) << 3);
            size_t goff = (size_t)(n0 + row) * 4096 + kg;
            load_lds16(c_hi + goff, &Bh[idx * 8]);
            load_lds16(c_lo + goff, &Bl[idx * 8]);
        }
        __syncthreads();   // drains vmcnt -> tile resident

        bf16x8 ah[4], al[4], bh[2], bl[2];
        #pragma unroll
        for (int mt = 0; mt < 4; ++mt) {
            int r = wm * 64 + mt * 16 + li;
            int byte = r * 64 + rslot;
            ah[mt] = *(const bf16x8*)((const char*)Ah + byte);
            al[mt] = *(const bf16x8*)((const char*)Al + byte);
        }
        #pragma unroll
        for (int nt = 0; nt < 2; ++nt) {
            int r = wn * 32 + nt * 16 + li;
            int byte = r * 64 + rslot;
            bh[nt] = *(const bf16x8*)((const char*)Bh + byte);
            bl[nt] = *(const bf16x8*)((const char*)Bl + byte);
        }
        #pragma unroll
        for (int mt = 0; mt < 4; ++mt)
            #pragma unroll
            for (int nt = 0; nt < 2; ++nt) {
                acc[mt][nt] = __builtin_amdgcn_mfma_f32_16x16x32_bf16(ah[mt], bh[nt], acc[mt][nt], 0, 0, 0);
                acc[mt][nt] = __builtin_amdgcn_mfma_f32_16x16x32_bf16(ah[mt], bl[nt], acc[mt][nt], 0, 0, 0);
                acc[mt][nt] = __builtin_amdgcn_mfma_f32_16x16x32_bf16(al[mt], bh[nt], acc[mt][nt], 0, 0, 0);
            }
        __syncthreads();   // before next-tile overwrite
    }

    // epilogue: argmin of (c2[n] - 2*dot) per row. C/D: col=lane&15, row=(lane>>4)*4+reg.
    #pragma unroll
    for (int mt = 0; mt < 4; ++mt) {
        #pragma unroll
        for (int reg = 0; reg < 4; ++reg) {
            unsigned long long best = ~0ULL;
            #pragma unroll
            for (int nt = 0; nt < 2; ++nt) {
                int n = n0 + wn * 32 + nt * 16 + li;
                if (n < 1000) {
                    float v = c2[n] - 2.0f * acc[mt][nt][reg];
                    unsigned bi = __float_as_uint(v);
                    bi = (bi & 0x80000000u) ? ~bi : (bi | 0x80000000u);
                    unsigned long long key = ((unsigned long long)bi << 32) | (unsigned)n;
                    if (key < best) best = key;
                }
            }
            #pragma unroll
            for (int d = 1; d < 16; d <<= 1) {
                unsigned long long o = __shfl_xor(best, d, 64);
                if (o < best) best = o;
            }
            if (li == 0) {
                int lr = wm * 64 + mt * 16 + ls * 4 + reg;
                atomicMin(&red[lr], best);
            }
        }
    }
    __syncthreads();
    if (tid < GBM) atomicMin(&packed[m0 + tid], red[tid]);
}

// ---------------------------------------------------------------------------
// Kernel 4: unpack argmin index
// ---------------------------------------------------------------------------
__global__ __launch_bounds__(256) void extract_kernel(
    const unsigned long long* __restrict__ packed, int* __restrict__ out)
{
    int i = blockIdx.x * 256 + threadIdx.x;
    out[i] = (int)(unsigned)(packed[i] & 0xFFFFFFFFull);
}

// ---------------------------------------------------------------------------
extern "C" void kernel_launch(void* const* d_in, const int* in_sizes, int n_in,
                              void* d_out, int out_size, void* d_ws, size_t ws_size,
                              hipStream_t stream)
{
    const float* x    = (const float*)d_in[0];
    const float* w1   = (const float*)d_in[1];
    const float* b1   = (const float*)d_in[2];
    const float* w2   = (const float*)d_in[3];
    const float* b2   = (const float*)d_in[4];
    const float* cent = (const float*)d_in[5];
    int* out = (int*)d_out;

    char* ws = (char*)d_ws;
    u16* f_hi = (u16*)(ws);                          // 4096*4096*2 = 33554432
    u16* f_lo = (u16*)(ws + 33554432);               // 33554432
    u16* c_hi = (u16*)(ws + 67108864);               // 1024*4096*2 = 8388608
    u16* c_lo = (u16*)(ws + 75497472);               // 8388608
    float* c2 = (float*)(ws + 83886080);             // 4096
    unsigned long long* packed =
        (unsigned long long*)(ws + 83890176);        // 32768
    // w2t aliased into c_hi's unused pad rows (1000..1023): 73728 B needed,
    // fits in 24*8192 = 196608 B. GEMM may read these bytes as bf16 garbage,
    // but those columns (n>=1000) are guarded out in the argmin epilogue.
    u16* w2t = c_hi + (size_t)1000 * 4096;

    hipMemsetAsync(packed, 0xFF, 4096 * sizeof(unsigned long long), stream);
    w2t_prep_kernel<<<144, 256, 0, stream>>>(w2, w2t);
    cent_prep_kernel<<<1000, 256, 0, stream>>>(cent, c_hi, c_lo, c2);
    conv_fused_kernel<<<4096, 256, 0, stream>>>(x, w1, b1, w2t, b2, f_hi, f_lo);
    gemm_argmin_mfma<<<512, 256, 0, stream>>>(f_hi, f_lo, c_hi, c_lo, c2, packed);
    extract_kernel<<<16, 256, 0, stream>>>(packed, out);
}